// Round 1
// baseline (4521.033 us; speedup 1.0000x reference)
//
#include <hip/hip_runtime.h>
#include <hip/hip_bf16.h>
#include <math.h>

#define NL 4
#define DMODEL 256
#define NH 8
#define FFDIM 1024
#define BB 4
#define SS 1024
#define HDIM 32
#define MROWS (BB * SS)   // 4096
#define LN_EPS 1e-5f

// ---------------------------------------------------------------------------
// GEMM: C[M,N] = A[M,K] @ W[K,N] + bias[N], optional ReLU.
// 64x64 tile, 256 threads, 4x4 micro-tile per thread, BK=16.
// M % 64 == 0, N % 64 == 0, K % 16 == 0 (holds for all shapes here).
// ---------------------------------------------------------------------------
template<int ACT>
__global__ __launch_bounds__(256)
void gemm_bias(const float* __restrict__ A, const float* __restrict__ W,
               const float* __restrict__ bias, float* __restrict__ C,
               int Mm, int N, int K)
{
    __shared__ float As[64][17];   // +1 pad: avoid 4-way bank conflict on a-reads
    __shared__ float Bs[16][64];   // b-reads are float4, 2-way conflict (free)

    const int tid = threadIdx.x;
    const int m0 = blockIdx.y * 64;
    const int n0 = blockIdx.x * 64;
    const int tx = tid & 15;       // 16 cols of threads
    const int ty = tid >> 4;       // 16 rows of threads

    float acc[4][4] = {};

    for (int k0 = 0; k0 < K; k0 += 16) {
        // Load A tile 64x16: 256 threads x float4
        {
            const int r = tid >> 2;
            const int c = (tid & 3) << 2;
            const float4 v = *reinterpret_cast<const float4*>(
                A + (size_t)(m0 + r) * K + k0 + c);
            As[r][c + 0] = v.x; As[r][c + 1] = v.y;
            As[r][c + 2] = v.z; As[r][c + 3] = v.w;
        }
        // Load B tile 16x64: 256 threads x float4 (coalesced)
        {
            const int r = tid >> 4;
            const int c = (tid & 15) << 2;
            const float4 v = *reinterpret_cast<const float4*>(
                W + (size_t)(k0 + r) * N + n0 + c);
            *reinterpret_cast<float4*>(&Bs[r][c]) = v;
        }
        __syncthreads();

        #pragma unroll
        for (int kk = 0; kk < 16; ++kk) {
            const float a0 = As[ty * 4 + 0][kk];
            const float a1 = As[ty * 4 + 1][kk];
            const float a2 = As[ty * 4 + 2][kk];
            const float a3 = As[ty * 4 + 3][kk];
            const float4 b = *reinterpret_cast<const float4*>(&Bs[kk][tx * 4]);
            acc[0][0] += a0 * b.x; acc[0][1] += a0 * b.y; acc[0][2] += a0 * b.z; acc[0][3] += a0 * b.w;
            acc[1][0] += a1 * b.x; acc[1][1] += a1 * b.y; acc[1][2] += a1 * b.z; acc[1][3] += a1 * b.w;
            acc[2][0] += a2 * b.x; acc[2][1] += a2 * b.y; acc[2][2] += a2 * b.z; acc[2][3] += a2 * b.w;
            acc[3][0] += a3 * b.x; acc[3][1] += a3 * b.y; acc[3][2] += a3 * b.z; acc[3][3] += a3 * b.w;
        }
        __syncthreads();
    }

    const float4 bv = *reinterpret_cast<const float4*>(bias + n0 + tx * 4);
    #pragma unroll
    for (int i = 0; i < 4; ++i) {
        const int row = m0 + ty * 4 + i;
        float4 o;
        o.x = acc[i][0] + bv.x;
        o.y = acc[i][1] + bv.y;
        o.z = acc[i][2] + bv.z;
        o.w = acc[i][3] + bv.w;
        if (ACT) {
            o.x = fmaxf(o.x, 0.f); o.y = fmaxf(o.y, 0.f);
            o.z = fmaxf(o.z, 0.f); o.w = fmaxf(o.w, 0.f);
        }
        *reinterpret_cast<float4*>(C + (size_t)row * N + n0 + tx * 4) = o;
    }
}

// ---------------------------------------------------------------------------
// Attention: one wave (64 lanes) per query row (b,h,q). 4 waves per block.
// qkv layout per token row: [q(0:256) | k(256:512) | v(512:768)].
// Online softmax over 16 chunks of 64 keys; each lane owns one key per chunk
// and keeps a 32-wide partial output accumulator; shuffle-reduced at the end.
// scale = 1 (reference uses raw q.k), mask==0 -> -3.4e38 (finfo.min).
// ---------------------------------------------------------------------------
__global__ __launch_bounds__(256)
void attn_kernel(const float* __restrict__ qkv, const int* __restrict__ mask,
                 float* __restrict__ out)
{
    const int wave = threadIdx.x >> 6;
    const int lane = threadIdx.x & 63;
    const int gidx = blockIdx.x * 4 + wave;   // (b*NH + h)*SS + q
    const int q  = gidx & (SS - 1);
    const int bh = gidx >> 10;
    const int h  = bh & (NH - 1);
    const int b  = bh >> 3;

    const size_t tok_stride = 3 * DMODEL;
    const float* qptr = qkv + ((size_t)b * SS + q) * tok_stride + h * HDIM;

    float qv[HDIM];
    #pragma unroll
    for (int i = 0; i < HDIM; i += 4) {
        const float4 t = *reinterpret_cast<const float4*>(qptr + i);
        qv[i] = t.x; qv[i + 1] = t.y; qv[i + 2] = t.z; qv[i + 3] = t.w;
    }

    float m = -3.4e38f;
    float ssum = 0.f;          // per-lane partial
    float oacc[HDIM] = {};     // per-lane partial output

    for (int k0 = 0; k0 < SS; k0 += 64) {
        const int k = k0 + lane;
        const float* kptr = qkv + ((size_t)b * SS + k) * tok_stride + DMODEL + h * HDIM;
        float s = 0.f;
        #pragma unroll
        for (int i = 0; i < HDIM; i += 4) {
            const float4 t = *reinterpret_cast<const float4*>(kptr + i);
            s += qv[i] * t.x + qv[i + 1] * t.y + qv[i + 2] * t.z + qv[i + 3] * t.w;
        }
        const bool masked = (mask[b * SS + k] == 0);
        if (masked) s = -3.4e38f;

        // wave-wide max of this chunk
        float mc = s;
        #pragma unroll
        for (int off = 32; off >= 1; off >>= 1)
            mc = fmaxf(mc, __shfl_xor(mc, off));
        const float mnew = fmaxf(m, mc);
        const float scale = __expf(m - mnew);   // first chunk: exp(-huge)=0
        ssum *= scale;
        #pragma unroll
        for (int i = 0; i < HDIM; ++i) oacc[i] *= scale;

        const float p = masked ? 0.f : __expf(s - mnew);
        ssum += p;

        const float* vptr = qkv + ((size_t)b * SS + k) * tok_stride + 2 * DMODEL + h * HDIM;
        #pragma unroll
        for (int i = 0; i < HDIM; i += 4) {
            const float4 t = *reinterpret_cast<const float4*>(vptr + i);
            oacc[i]     += p * t.x;
            oacc[i + 1] += p * t.y;
            oacc[i + 2] += p * t.z;
            oacc[i + 3] += p * t.w;
        }
        m = mnew;
    }

    // cross-lane reduce
    #pragma unroll
    for (int off = 32; off >= 1; off >>= 1) {
        ssum += __shfl_xor(ssum, off);
        #pragma unroll
        for (int i = 0; i < HDIM; ++i)
            oacc[i] += __shfl_xor(oacc[i], off);
    }

    if (lane == 0) {
        const float inv = 1.f / ssum;
        float* optr = out + ((size_t)b * SS + q) * DMODEL + h * HDIM;
        #pragma unroll
        for (int i = 0; i < HDIM; i += 4) {
            float4 o;
            o.x = oacc[i] * inv; o.y = oacc[i + 1] * inv;
            o.z = oacc[i + 2] * inv; o.w = oacc[i + 3] * inv;
            *reinterpret_cast<float4*>(optr + i) = o;
        }
    }
}

// ---------------------------------------------------------------------------
// out = LayerNorm(a + r) * g + beta, rows of 256. One wave per row.
// ---------------------------------------------------------------------------
__global__ __launch_bounds__(256)
void add_ln_kernel(const float* __restrict__ a, const float* __restrict__ r,
                   const float* __restrict__ g, const float* __restrict__ beta,
                   float* __restrict__ out)
{
    const int wave = threadIdx.x >> 6;
    const int lane = threadIdx.x & 63;
    const int row = blockIdx.x * 4 + wave;
    const size_t off = (size_t)row * DMODEL + lane * 4;

    const float4 va = *reinterpret_cast<const float4*>(a + off);
    const float4 vr = *reinterpret_cast<const float4*>(r + off);
    float v[4] = { va.x + vr.x, va.y + vr.y, va.z + vr.z, va.w + vr.w };

    float s = v[0] + v[1] + v[2] + v[3];
    #pragma unroll
    for (int o = 32; o >= 1; o >>= 1) s += __shfl_xor(s, o);
    const float mean = s * (1.f / DMODEL);

    float d0 = v[0] - mean, d1 = v[1] - mean, d2 = v[2] - mean, d3 = v[3] - mean;
    float sq = d0 * d0 + d1 * d1 + d2 * d2 + d3 * d3;
    #pragma unroll
    for (int o = 32; o >= 1; o >>= 1) sq += __shfl_xor(sq, o);
    const float inv = rsqrtf(sq * (1.f / DMODEL) + LN_EPS);

    const float4 vg = *reinterpret_cast<const float4*>(g + lane * 4);
    const float4 vb = *reinterpret_cast<const float4*>(beta + lane * 4);
    float4 o4;
    o4.x = d0 * inv * vg.x + vb.x;
    o4.y = d1 * inv * vg.y + vb.y;
    o4.z = d2 * inv * vg.z + vb.z;
    o4.w = d3 * inv * vg.w + vb.w;
    *reinterpret_cast<float4*>(out + off) = o4;
}

// ---------------------------------------------------------------------------
extern "C" void kernel_launch(void* const* d_in, const int* in_sizes, int n_in,
                              void* d_out, int out_size, void* d_ws, size_t ws_size,
                              hipStream_t stream)
{
    const float* x_in   = (const float*)d_in[0];
    const int*   maskp  = (const int*)d_in[1];
    const float* qkv_w  = (const float*)d_in[2];
    const float* qkv_b  = (const float*)d_in[3];
    const float* fc_w   = (const float*)d_in[4];
    const float* fc_b   = (const float*)d_in[5];
    const float* ln1_g  = (const float*)d_in[6];
    const float* ln1_b  = (const float*)d_in[7];
    const float* ln2_g  = (const float*)d_in[8];
    const float* ln2_b  = (const float*)d_in[9];
    const float* ff1_w  = (const float*)d_in[10];
    const float* ff1_b  = (const float*)d_in[11];
    const float* ff2_w  = (const float*)d_in[12];
    const float* ff2_b  = (const float*)d_in[13];

    float* x = (float*)d_out;                     // [MROWS, DMODEL], persistent
    float* ws = (float*)d_ws;
    float* big  = ws;                             // 16MB: qkv [4096,768] then h [4096,1024]
    float* attn = ws + (size_t)MROWS * FFDIM;     // 4MB: attn output [4096,256]
    float* o2   = attn + (size_t)MROWS * DMODEL;  // 4MB: fc/ff2 output [4096,256]

    hipMemcpyAsync(x, x_in, sizeof(float) * MROWS * DMODEL,
                   hipMemcpyDeviceToDevice, stream);

    for (int l = 0; l < NL; ++l) {
        // qkv = x @ qkv_w[l] + qkv_b[l]        [4096, 768]
        gemm_bias<0><<<dim3(12, 64), 256, 0, stream>>>(
            x, qkv_w + (size_t)l * DMODEL * 3 * DMODEL, qkv_b + l * 3 * DMODEL,
            big, MROWS, 3 * DMODEL, DMODEL);
        // attention -> attn [4096, 256]
        attn_kernel<<<dim3(MROWS * NH / 4), 256, 0, stream>>>(big, maskp, attn);
        // o2 = attn @ fc_w[l] + fc_b[l]        [4096, 256]
        gemm_bias<0><<<dim3(4, 64), 256, 0, stream>>>(
            attn, fc_w + (size_t)l * DMODEL * DMODEL, fc_b + l * DMODEL,
            o2, MROWS, DMODEL, DMODEL);
        // x = LN1(o2 + x)
        add_ln_kernel<<<dim3(MROWS / 4), 256, 0, stream>>>(
            o2, x, ln1_g + l * DMODEL, ln1_b + l * DMODEL, x);
        // h = relu(x @ ff1_w[l] + ff1_b[l])    [4096, 1024]
        gemm_bias<1><<<dim3(16, 64), 256, 0, stream>>>(
            x, ff1_w + (size_t)l * DMODEL * FFDIM, ff1_b + l * FFDIM,
            big, MROWS, FFDIM, DMODEL);
        // o2 = h @ ff2_w[l] + ff2_b[l]         [4096, 256]
        gemm_bias<0><<<dim3(4, 64), 256, 0, stream>>>(
            big, ff2_w + (size_t)l * FFDIM * DMODEL, ff2_b + l * DMODEL,
            o2, MROWS, DMODEL, FFDIM);
        // x = LN2(x + o2)
        add_ln_kernel<<<dim3(MROWS / 4), 256, 0, stream>>>(
            o2, x, ln2_g + l * DMODEL, ln2_b + l * DMODEL, x);
    }
}

// Round 2
// 908.904 us; speedup vs baseline: 4.9742x; 4.9742x over previous
//
#include <hip/hip_runtime.h>
#include <hip/hip_bf16.h>
#include <math.h>

#define NL 4
#define DMODEL 256
#define NH 8
#define FFDIM 1024
#define BB 4
#define SS 1024
#define HDIM 32
#define MROWS (BB * SS)   // 4096
#define LN_EPS 1e-5f

typedef __bf16 bf16x8 __attribute__((ext_vector_type(8)));
typedef float f32x4 __attribute__((ext_vector_type(4)));

__device__ __forceinline__ ushort f2bf(float f) {
    uint u = __builtin_bit_cast(uint, f);
    u += 0x7fff + ((u >> 16) & 1);          // round-to-nearest-even
    return (ushort)(u >> 16);
}
__device__ __forceinline__ uint pack2(float a, float b) {
    return (uint)f2bf(a) | ((uint)f2bf(b) << 16);
}

// ---------------------------------------------------------------------------
// GEMM: C[M,N] = A[M,K] @ W[K,N] + bias[N], optional ReLU. (fp32, unchanged)
// ---------------------------------------------------------------------------
template<int ACT>
__global__ __launch_bounds__(256)
void gemm_bias(const float* __restrict__ A, const float* __restrict__ W,
               const float* __restrict__ bias, float* __restrict__ C,
               int Mm, int N, int K)
{
    __shared__ float As[64][17];
    __shared__ float Bs[16][64];

    const int tid = threadIdx.x;
    const int m0 = blockIdx.y * 64;
    const int n0 = blockIdx.x * 64;
    const int tx = tid & 15;
    const int ty = tid >> 4;

    float acc[4][4] = {};

    for (int k0 = 0; k0 < K; k0 += 16) {
        {
            const int r = tid >> 2;
            const int c = (tid & 3) << 2;
            const float4 v = *reinterpret_cast<const float4*>(
                A + (size_t)(m0 + r) * K + k0 + c);
            As[r][c + 0] = v.x; As[r][c + 1] = v.y;
            As[r][c + 2] = v.z; As[r][c + 3] = v.w;
        }
        {
            const int r = tid >> 4;
            const int c = (tid & 15) << 2;
            const float4 v = *reinterpret_cast<const float4*>(
                W + (size_t)(k0 + r) * N + n0 + c);
            *reinterpret_cast<float4*>(&Bs[r][c]) = v;
        }
        __syncthreads();

        #pragma unroll
        for (int kk = 0; kk < 16; ++kk) {
            const float a0 = As[ty * 4 + 0][kk];
            const float a1 = As[ty * 4 + 1][kk];
            const float a2 = As[ty * 4 + 2][kk];
            const float a3 = As[ty * 4 + 3][kk];
            const float4 b = *reinterpret_cast<const float4*>(&Bs[kk][tx * 4]);
            acc[0][0] += a0 * b.x; acc[0][1] += a0 * b.y; acc[0][2] += a0 * b.z; acc[0][3] += a0 * b.w;
            acc[1][0] += a1 * b.x; acc[1][1] += a1 * b.y; acc[1][2] += a1 * b.z; acc[1][3] += a1 * b.w;
            acc[2][0] += a2 * b.x; acc[2][1] += a2 * b.y; acc[2][2] += a2 * b.z; acc[2][3] += a2 * b.w;
            acc[3][0] += a3 * b.x; acc[3][1] += a3 * b.y; acc[3][2] += a3 * b.z; acc[3][3] += a3 * b.w;
        }
        __syncthreads();
    }

    const float4 bv = *reinterpret_cast<const float4*>(bias + n0 + tx * 4);
    #pragma unroll
    for (int i = 0; i < 4; ++i) {
        const int row = m0 + ty * 4 + i;
        float4 o;
        o.x = acc[i][0] + bv.x;
        o.y = acc[i][1] + bv.y;
        o.z = acc[i][2] + bv.z;
        o.w = acc[i][3] + bv.w;
        if (ACT) {
            o.x = fmaxf(o.x, 0.f); o.y = fmaxf(o.y, 0.f);
            o.z = fmaxf(o.z, 0.f); o.w = fmaxf(o.w, 0.f);
        }
        *reinterpret_cast<float4*>(C + (size_t)row * N + n0 + tx * 4) = o;
    }
}

// ---------------------------------------------------------------------------
// MFMA flash attention. One wave (64 threads) per 16-query tile of one (b,h).
// qkv fp32 row layout per token: [q 0:256 | k 256:512 | v 512:768].
// Per 32-key chunk: stage K[32][32] and V^T[32][32] as bf16 in LDS,
// S-tiles = mfma_16x16x32(Q, K^T), online softmax in-register (per 16-lane
// group), P -> LDS (bf16) -> A-fragment, O += mfma(P, V).
// Fragment layouts (gfx950, 16x16x32):
//   A: row = lane&15, k = (lane>>4)*8 + i
//   B: col = lane&15, k = (lane>>4)*8 + i
//   C/D: col = lane&15, row = (lane>>4)*4 + reg     [verified m89/m91]
// ---------------------------------------------------------------------------
__global__ __launch_bounds__(64)
void attn_mfma(const float* __restrict__ qkv, const int* __restrict__ mask,
               float* __restrict__ out)
{
    const int lane = threadIdx.x;
    const int qt = blockIdx.x & 63;       // 64 query tiles of 16
    const int bh = blockIdx.x >> 6;       // 0..31
    const int h = bh & (NH - 1);
    const int b = bh >> 3;
    const int q0 = qt * 16;

    __shared__ ushort Kl[32][40];   // K chunk,  row = key,  col = dim (pad 40)
    __shared__ ushort Vt[32][40];   // V chunk transposed: row = dim, col = key
    __shared__ ushort Pl[16][40];   // P tile: row = q_local, col = key_local

    const int g = lane >> 4;        // 0..3
    const int c = lane & 15;        // 0..15

    // Q fragment: lane holds Q[q0 + c][g*8 .. g*8+8)
    bf16x8 qfrag;
    {
        const float* qp = qkv + ((size_t)(b * SS + q0 + c)) * 768 + h * HDIM + g * 8;
        const float4 f0 = ((const float4*)qp)[0];
        const float4 f1 = ((const float4*)qp)[1];
        uint2 lo = make_uint2(pack2(f0.x, f0.y), pack2(f0.z, f0.w));
        uint2 hi = make_uint2(pack2(f1.x, f1.y), pack2(f1.z, f1.w));
        uint4 all = make_uint4(lo.x, lo.y, hi.x, hi.y);
        qfrag = __builtin_bit_cast(bf16x8, all);
    }

    float m[4]    = { -3.4e38f, -3.4e38f, -3.4e38f, -3.4e38f };
    float lsum[4] = { 0.f, 0.f, 0.f, 0.f };
    f32x4 oacc0 = { 0.f, 0.f, 0.f, 0.f };
    f32x4 oacc1 = { 0.f, 0.f, 0.f, 0.f };
    const f32x4 zf = { 0.f, 0.f, 0.f, 0.f };

    for (int k0 = 0; k0 < SS; k0 += 32) {
        __syncthreads();
        // ---- stage K chunk: lane covers key = lane>>1, dim half (lane&1)*16
        {
            const int key = lane >> 1;
            const int d0 = (lane & 1) << 4;
            const float* kp = qkv + ((size_t)(b * SS + k0 + key)) * 768
                              + DMODEL + h * HDIM + d0;
            const float4 f0 = ((const float4*)kp)[0];
            const float4 f1 = ((const float4*)kp)[1];
            const float4 f2 = ((const float4*)kp)[2];
            const float4 f3 = ((const float4*)kp)[3];
            uint2* dst = (uint2*)&Kl[key][d0];
            dst[0] = make_uint2(pack2(f0.x, f0.y), pack2(f0.z, f0.w));
            dst[1] = make_uint2(pack2(f1.x, f1.y), pack2(f1.z, f1.w));
            dst[2] = make_uint2(pack2(f2.x, f2.y), pack2(f2.z, f2.w));
            dst[3] = make_uint2(pack2(f3.x, f3.y), pack2(f3.z, f3.w));
        }
        // ---- stage V chunk transposed: lane covers dim = lane>>1, key half
        {
            const int d = lane >> 1;
            const int ks = (lane & 1) << 4;
            const float* vp = qkv + ((size_t)(b * SS + k0 + ks)) * 768
                              + 2 * DMODEL + h * HDIM + d;
            uint2* dst = (uint2*)&Vt[d][ks];
            #pragma unroll
            for (int j = 0; j < 4; ++j) {
                const float a0 = vp[(4 * j + 0) * 768];
                const float a1 = vp[(4 * j + 1) * 768];
                const float a2 = vp[(4 * j + 2) * 768];
                const float a3 = vp[(4 * j + 3) * 768];
                dst[j] = make_uint2(pack2(a0, a1), pack2(a2, a3));
            }
        }
        __syncthreads();

        // ---- QK^T: two 16x16 score tiles (keys k0..k0+15, k0+16..k0+31)
        const bf16x8 kf0 = *(const bf16x8*)&Kl[c][g * 8];
        const bf16x8 kf1 = *(const bf16x8*)&Kl[16 + c][g * 8];
        f32x4 s0 = __builtin_amdgcn_mfma_f32_16x16x32_bf16(qfrag, kf0, zf, 0, 0, 0);
        f32x4 s1 = __builtin_amdgcn_mfma_f32_16x16x32_bf16(qfrag, kf1, zf, 0, 0, 0);

        // ---- mask (key-wise)
        const int mk0 = mask[b * SS + k0 + c];
        const int mk1 = mask[b * SS + k0 + 16 + c];
        #pragma unroll
        for (int r = 0; r < 4; ++r) {
            s0[r] = mk0 ? s0[r] : -3.4e38f;
            s1[r] = mk1 ? s1[r] : -3.4e38f;
        }

        // ---- online softmax (per 16-lane group; rows q = g*4 + r)
        float mx[4];
        #pragma unroll
        for (int r = 0; r < 4; ++r) mx[r] = fmaxf(s0[r], s1[r]);
        #pragma unroll
        for (int off = 1; off < 16; off <<= 1) {
            #pragma unroll
            for (int r = 0; r < 4; ++r)
                mx[r] = fmaxf(mx[r], __shfl_xor(mx[r], off));
        }
        #pragma unroll
        for (int r = 0; r < 4; ++r) {
            const float mn = fmaxf(m[r], mx[r]);
            const float sc = __expf(m[r] - mn);
            m[r] = mn;
            lsum[r] *= sc;
            oacc0[r] *= sc;
            oacc1[r] *= sc;
            const float p0 = mk0 ? __expf(s0[r] - mn) : 0.f;
            const float p1 = mk1 ? __expf(s1[r] - mn) : 0.f;
            lsum[r] += p0 + p1;
            Pl[g * 4 + r][c]      = f2bf(p0);
            Pl[g * 4 + r][16 + c] = f2bf(p1);
        }

        // ---- PV: O[16q][32d] += P[16q][32k] @ V[32k][32d]
        const bf16x8 pf  = *(const bf16x8*)&Pl[c][g * 8];
        const bf16x8 vf0 = *(const bf16x8*)&Vt[c][g * 8];
        const bf16x8 vf1 = *(const bf16x8*)&Vt[16 + c][g * 8];
        oacc0 = __builtin_amdgcn_mfma_f32_16x16x32_bf16(pf, vf0, oacc0, 0, 0, 0);
        oacc1 = __builtin_amdgcn_mfma_f32_16x16x32_bf16(pf, vf1, oacc1, 0, 0, 0);
    }

    // ---- finalize: reduce denominators across the 16-lane group, store
    #pragma unroll
    for (int off = 1; off < 16; off <<= 1) {
        #pragma unroll
        for (int r = 0; r < 4; ++r)
            lsum[r] += __shfl_xor(lsum[r], off);
    }
    #pragma unroll
    for (int r = 0; r < 4; ++r) {
        const float inv = 1.f / lsum[r];
        float* op = out + ((size_t)(b * SS + q0 + g * 4 + r)) * DMODEL + h * HDIM;
        op[c]      = oacc0[r] * inv;
        op[16 + c] = oacc1[r] * inv;
    }
}

// ---------------------------------------------------------------------------
// out = LayerNorm(a + r) * g + beta, rows of 256. One wave per row. (unchanged)
// ---------------------------------------------------------------------------
__global__ __launch_bounds__(256)
void add_ln_kernel(const float* __restrict__ a, const float* __restrict__ r,
                   const float* __restrict__ g, const float* __restrict__ beta,
                   float* __restrict__ out)
{
    const int wave = threadIdx.x >> 6;
    const int lane = threadIdx.x & 63;
    const int row = blockIdx.x * 4 + wave;
    const size_t off = (size_t)row * DMODEL + lane * 4;

    const float4 va = *reinterpret_cast<const float4*>(a + off);
    const float4 vr = *reinterpret_cast<const float4*>(r + off);
    float v[4] = { va.x + vr.x, va.y + vr.y, va.z + vr.z, va.w + vr.w };

    float s = v[0] + v[1] + v[2] + v[3];
    #pragma unroll
    for (int o = 32; o >= 1; o >>= 1) s += __shfl_xor(s, o);
    const float mean = s * (1.f / DMODEL);

    float d0 = v[0] - mean, d1 = v[1] - mean, d2 = v[2] - mean, d3 = v[3] - mean;
    float sq = d0 * d0 + d1 * d1 + d2 * d2 + d3 * d3;
    #pragma unroll
    for (int o = 32; o >= 1; o >>= 1) sq += __shfl_xor(sq, o);
    const float inv = rsqrtf(sq * (1.f / DMODEL) + LN_EPS);

    const float4 vg = *reinterpret_cast<const float4*>(g + lane * 4);
    const float4 vb = *reinterpret_cast<const float4*>(beta + lane * 4);
    float4 o4;
    o4.x = d0 * inv * vg.x + vb.x;
    o4.y = d1 * inv * vg.y + vb.y;
    o4.z = d2 * inv * vg.z + vb.z;
    o4.w = d3 * inv * vg.w + vb.w;
    *reinterpret_cast<float4*>(out + off) = o4;
}

// ---------------------------------------------------------------------------
extern "C" void kernel_launch(void* const* d_in, const int* in_sizes, int n_in,
                              void* d_out, int out_size, void* d_ws, size_t ws_size,
                              hipStream_t stream)
{
    const float* x_in   = (const float*)d_in[0];
    const int*   maskp  = (const int*)d_in[1];
    const float* qkv_w  = (const float*)d_in[2];
    const float* qkv_b  = (const float*)d_in[3];
    const float* fc_w   = (const float*)d_in[4];
    const float* fc_b   = (const float*)d_in[5];
    const float* ln1_g  = (const float*)d_in[6];
    const float* ln1_b  = (const float*)d_in[7];
    const float* ln2_g  = (const float*)d_in[8];
    const float* ln2_b  = (const float*)d_in[9];
    const float* ff1_w  = (const float*)d_in[10];
    const float* ff1_b  = (const float*)d_in[11];
    const float* ff2_w  = (const float*)d_in[12];
    const float* ff2_b  = (const float*)d_in[13];

    float* x = (float*)d_out;                     // [MROWS, DMODEL], persistent
    float* ws = (float*)d_ws;
    float* big  = ws;                             // 16MB: qkv [4096,768] then h [4096,1024]
    float* attn = ws + (size_t)MROWS * FFDIM;     // 4MB: attn output [4096,256]
    float* o2   = attn + (size_t)MROWS * DMODEL;  // 4MB: fc/ff2 output [4096,256]

    hipMemcpyAsync(x, x_in, sizeof(float) * MROWS * DMODEL,
                   hipMemcpyDeviceToDevice, stream);

    for (int l = 0; l < NL; ++l) {
        // qkv = x @ qkv_w[l] + qkv_b[l]        [4096, 768]
        gemm_bias<0><<<dim3(12, 64), 256, 0, stream>>>(
            x, qkv_w + (size_t)l * DMODEL * 3 * DMODEL, qkv_b + l * 3 * DMODEL,
            big, MROWS, 3 * DMODEL, DMODEL);
        // attention -> attn [4096, 256]
        attn_mfma<<<dim3(32 * 64), 64, 0, stream>>>(big, maskp, attn);
        // o2 = attn @ fc_w[l] + fc_b[l]        [4096, 256]
        gemm_bias<0><<<dim3(4, 64), 256, 0, stream>>>(
            attn, fc_w + (size_t)l * DMODEL * DMODEL, fc_b + l * DMODEL,
            o2, MROWS, DMODEL, DMODEL);
        // x = LN1(o2 + x)
        add_ln_kernel<<<dim3(MROWS / 4), 256, 0, stream>>>(
            o2, x, ln1_g + l * DMODEL, ln1_b + l * DMODEL, x);
        // h = relu(x @ ff1_w[l] + ff1_b[l])    [4096, 1024]
        gemm_bias<1><<<dim3(16, 64), 256, 0, stream>>>(
            x, ff1_w + (size_t)l * DMODEL * FFDIM, ff1_b + l * FFDIM,
            big, MROWS, FFDIM, DMODEL);
        // o2 = h @ ff2_w[l] + ff2_b[l]         [4096, 256]
        gemm_bias<0><<<dim3(4, 64), 256, 0, stream>>>(
            big, ff2_w + (size_t)l * FFDIM * DMODEL, ff2_b + l * DMODEL,
            o2, MROWS, DMODEL, FFDIM);
        // x = LN2(x + o2)
        add_ln_kernel<<<dim3(MROWS / 4), 256, 0, stream>>>(
            o2, x, ln2_g + l * DMODEL, ln2_b + l * DMODEL, x);
    }
}

// Round 3
// 456.047 us; speedup vs baseline: 9.9135x; 1.9930x over previous
//
#include <hip/hip_runtime.h>
#include <hip/hip_bf16.h>
#include <math.h>

#define NL 4
#define DMODEL 256
#define NH 8
#define FFDIM 1024
#define BB 4
#define SS 1024
#define HDIM 32
#define MROWS (BB * SS)   // 4096
#define LN_EPS 1e-5f

typedef __bf16 bf16x8 __attribute__((ext_vector_type(8)));
typedef float f32x4 __attribute__((ext_vector_type(4)));
typedef unsigned int u32;

__device__ __forceinline__ ushort f2bf(float f) {
    uint u = __builtin_bit_cast(uint, f);
    u += 0x7fff + ((u >> 16) & 1);          // round-to-nearest-even
    return (ushort)(u >> 16);
}
__device__ __forceinline__ uint pack2(float a, float b) {
    return (uint)f2bf(a) | ((uint)f2bf(b) << 16);
}

// async global->LDS, 16B per lane (wave-uniform LDS base + lane*16 layout)
__device__ __forceinline__ void async_ld16(const void* g, void* l) {
    __builtin_amdgcn_global_load_lds(
        (const __attribute__((address_space(1))) u32*)g,
        (__attribute__((address_space(3))) u32*)l, 16, 0, 0);
}

// ---------------------------------------------------------------------------
// Weight convert+transpose: W[K][N] fp32 -> WT[N][K] bf16.  blockIdx.z = layer.
// ---------------------------------------------------------------------------
__global__ __launch_bounds__(256)
void wconvT(const float* __restrict__ W, ushort* __restrict__ WT, int K, int N)
{
    const int l = blockIdx.z;
    const float* src = W + (size_t)l * K * N;
    ushort* dst = WT + (size_t)l * K * N;
    __shared__ ushort t[32][33];
    const int n0 = blockIdx.x * 32, k0 = blockIdx.y * 32;
    const int tn = threadIdx.x & 31, tk8 = threadIdx.x >> 5;   // 0..31, 0..7
    #pragma unroll
    for (int i = 0; i < 4; ++i) {
        const int k = k0 + tk8 + i * 8;
        t[tn][tk8 + i * 8] = f2bf(src[(size_t)k * N + n0 + tn]);
    }
    __syncthreads();
    #pragma unroll
    for (int i = 0; i < 4; ++i) {
        const int n = n0 + tk8 + i * 8;
        dst[(size_t)n * K + k0 + tn] = t[tk8 + i * 8][tn];
    }
}

// ---------------------------------------------------------------------------
// x_in fp32 -> x fp32 (d_out residual stream) + x_bf bf16 mirror
// ---------------------------------------------------------------------------
__global__ __launch_bounds__(256)
void convert_x(const float* __restrict__ xin, float* __restrict__ x,
               ushort* __restrict__ xb)
{
    const size_t i = ((size_t)blockIdx.x * 256 + threadIdx.x) * 4;
    const float4 v = *reinterpret_cast<const float4*>(xin + i);
    *reinterpret_cast<float4*>(x + i) = v;
    uint2 p = make_uint2(pack2(v.x, v.y), pack2(v.z, v.w));
    *reinterpret_cast<uint2*>(xb + i) = p;
}

// ---------------------------------------------------------------------------
// MFMA GEMM: C[M,N] = A[M,K](bf16) @ WT[N,K](bf16)^T + bias, opt ReLU.
// BM=128, BK=64, BN template {128,64}. 256 threads = 4 waves.
// BN=128: waves 2x2, each 64x64 (4x4 frags). BN=64: waves 4x1, each 32x64.
// OBF=1 -> write bf16 to Cb; else fp32 to Cf.
// Fragment layouts (16x16x32): A row=lane&15,k=(lane>>4)*8+i; B col=lane&15,
// same k; C/D col=lane&15,row=(lane>>4)*4+reg.  [verified on-HW rounds 1-2]
// ---------------------------------------------------------------------------
template<int BN, int ACT, int OBF>
__global__ __launch_bounds__(256)
void gemm_mfma(const ushort* __restrict__ A, const ushort* __restrict__ WT,
               const float* __restrict__ bias, float* __restrict__ Cf,
               ushort* __restrict__ Cb, int N, int K)
{
    constexpr int BM = 128, BK = 64;
    __shared__ __align__(16) ushort As[BM * BK];   // [128][64]
    __shared__ __align__(16) ushort Bs[BN * BK];   // [BN][64]

    const int tid = threadIdx.x;
    const int m0 = blockIdx.y * BM;
    const int n0 = blockIdx.x * BN;
    const int wid = tid >> 6, lane = tid & 63;
    const int g = lane >> 4, c = lane & 15;

    constexpr int WR = (BN == 128) ? 64 : 32;   // rows per wave
    constexpr int MR = WR / 16;                  // row frags
    constexpr int NR = 4;                        // col frags (64 cols)
    const int wr = (BN == 128) ? (wid >> 1) : wid;
    const int wc = (BN == 128) ? (wid & 1) : 0;

    f32x4 acc[MR][NR] = {};

    for (int k0 = 0; k0 < K; k0 += BK) {
        #pragma unroll
        for (int it = 0; it < 4; ++it) {              // A: 16KB
            const int o = tid * 16 + it * 4096;
            const int r = o >> 7, cb = o & 127;
            async_ld16(A + (size_t)(m0 + r) * K + k0 + (cb >> 1), (char*)As + o);
        }
        #pragma unroll
        for (int it = 0; it < (BN * BK * 2) / 4096; ++it) {   // B
            const int o = tid * 16 + it * 4096;
            const int r = o >> 7, cb = o & 127;
            async_ld16(WT + (size_t)(n0 + r) * K + k0 + (cb >> 1), (char*)Bs + o);
        }
        __syncthreads();

        #pragma unroll
        for (int ks = 0; ks < 2; ++ks) {
            bf16x8 af[MR], bfr[NR];
            #pragma unroll
            for (int mi = 0; mi < MR; ++mi)
                af[mi] = *(const bf16x8*)&As[(wr * WR + mi * 16 + c) * BK + ks * 32 + g * 8];
            #pragma unroll
            for (int ni = 0; ni < NR; ++ni)
                bfr[ni] = *(const bf16x8*)&Bs[(wc * 64 + ni * 16 + c) * BK + ks * 32 + g * 8];
            #pragma unroll
            for (int mi = 0; mi < MR; ++mi)
                #pragma unroll
                for (int ni = 0; ni < NR; ++ni)
                    acc[mi][ni] = __builtin_amdgcn_mfma_f32_16x16x32_bf16(
                        af[mi], bfr[ni], acc[mi][ni], 0, 0, 0);
        }
        __syncthreads();
    }

    float bv[NR];
    #pragma unroll
    for (int ni = 0; ni < NR; ++ni)
        bv[ni] = bias[n0 + wc * 64 + ni * 16 + c];

    #pragma unroll
    for (int mi = 0; mi < MR; ++mi) {
        #pragma unroll
        for (int j = 0; j < 4; ++j) {
            const int row = m0 + wr * WR + mi * 16 + g * 4 + j;
            #pragma unroll
            for (int ni = 0; ni < NR; ++ni) {
                float v = acc[mi][ni][j] + bv[ni];
                if (ACT) v = fmaxf(v, 0.f);
                const int col = n0 + wc * 64 + ni * 16 + c;
                if (OBF) Cb[(size_t)row * N + col] = f2bf(v);
                else     Cf[(size_t)row * N + col] = v;
            }
        }
    }
}

// ---------------------------------------------------------------------------
// MFMA flash attention, bf16 qkv input [4096][768], bf16 output [4096][256].
// One wave per 16-query tile. Structure verified in round 2.
// ---------------------------------------------------------------------------
__global__ __launch_bounds__(64)
void attn_mfma(const ushort* __restrict__ qkv, const int* __restrict__ mask,
               ushort* __restrict__ out)
{
    const int lane = threadIdx.x;
    const int qt = blockIdx.x & 63;
    const int bh = blockIdx.x >> 6;
    const int h = bh & (NH - 1);
    const int b = bh >> 3;
    const int q0 = qt * 16;

    __shared__ __align__(16) ushort Kl[32][40];
    __shared__ __align__(16) ushort Vt[32][40];
    __shared__ __align__(16) ushort Pl[16][40];

    const int g = lane >> 4;
    const int c = lane & 15;

    // Q fragment: lane holds Q[q0+c][g*8 .. g*8+8)
    const bf16x8 qfrag = *(const bf16x8*)(
        qkv + ((size_t)(b * SS + q0 + c)) * 768 + h * HDIM + g * 8);

    float m[4]    = { -3.4e38f, -3.4e38f, -3.4e38f, -3.4e38f };
    float lsum[4] = { 0.f, 0.f, 0.f, 0.f };
    f32x4 oacc0 = { 0.f, 0.f, 0.f, 0.f };
    f32x4 oacc1 = { 0.f, 0.f, 0.f, 0.f };
    const f32x4 zf = { 0.f, 0.f, 0.f, 0.f };

    for (int k0 = 0; k0 < SS; k0 += 32) {
        __syncthreads();
        {   // stage K chunk: lane covers key=lane>>1, dim half (lane&1)*16
            const int key = lane >> 1;
            const int d0 = (lane & 1) << 4;
            const ushort* kp = qkv + ((size_t)(b * SS + k0 + key)) * 768
                               + DMODEL + h * HDIM + d0;
            const uint4 v0 = ((const uint4*)kp)[0];
            const uint4 v1 = ((const uint4*)kp)[1];
            uint4* dst = (uint4*)&Kl[key][d0];
            dst[0] = v0; dst[1] = v1;
        }
        {   // stage V transposed: lane covers dim=lane>>1, key half
            const int d = lane >> 1;
            const int ks = (lane & 1) << 4;
            const ushort* vp = qkv + ((size_t)(b * SS + k0 + ks)) * 768
                               + 2 * DMODEL + h * HDIM + d;
            uint2* dst = (uint2*)&Vt[d][ks];
            #pragma unroll
            for (int j = 0; j < 4; ++j) {
                const uint a0 = vp[(4 * j + 0) * 768];
                const uint a1 = vp[(4 * j + 1) * 768];
                const uint a2 = vp[(4 * j + 2) * 768];
                const uint a3 = vp[(4 * j + 3) * 768];
                dst[j] = make_uint2(a0 | (a1 << 16), a2 | (a3 << 16));
            }
        }
        __syncthreads();

        const bf16x8 kf0 = *(const bf16x8*)&Kl[c][g * 8];
        const bf16x8 kf1 = *(const bf16x8*)&Kl[16 + c][g * 8];
        f32x4 s0 = __builtin_amdgcn_mfma_f32_16x16x32_bf16(qfrag, kf0, zf, 0, 0, 0);
        f32x4 s1 = __builtin_amdgcn_mfma_f32_16x16x32_bf16(qfrag, kf1, zf, 0, 0, 0);

        const int mk0 = mask[b * SS + k0 + c];
        const int mk1 = mask[b * SS + k0 + 16 + c];
        #pragma unroll
        for (int r = 0; r < 4; ++r) {
            s0[r] = mk0 ? s0[r] : -3.4e38f;
            s1[r] = mk1 ? s1[r] : -3.4e38f;
        }

        float mx[4];
        #pragma unroll
        for (int r = 0; r < 4; ++r) mx[r] = fmaxf(s0[r], s1[r]);
        #pragma unroll
        for (int off = 1; off < 16; off <<= 1) {
            #pragma unroll
            for (int r = 0; r < 4; ++r)
                mx[r] = fmaxf(mx[r], __shfl_xor(mx[r], off));
        }
        #pragma unroll
        for (int r = 0; r < 4; ++r) {
            const float mn = fmaxf(m[r], mx[r]);
            const float sc = __expf(m[r] - mn);
            m[r] = mn;
            lsum[r] *= sc;
            oacc0[r] *= sc;
            oacc1[r] *= sc;
            const float p0 = mk0 ? __expf(s0[r] - mn) : 0.f;
            const float p1 = mk1 ? __expf(s1[r] - mn) : 0.f;
            lsum[r] += p0 + p1;
            Pl[g * 4 + r][c]      = f2bf(p0);
            Pl[g * 4 + r][16 + c] = f2bf(p1);
        }

        const bf16x8 pf  = *(const bf16x8*)&Pl[c][g * 8];
        const bf16x8 vf0 = *(const bf16x8*)&Vt[c][g * 8];
        const bf16x8 vf1 = *(const bf16x8*)&Vt[16 + c][g * 8];
        oacc0 = __builtin_amdgcn_mfma_f32_16x16x32_bf16(pf, vf0, oacc0, 0, 0, 0);
        oacc1 = __builtin_amdgcn_mfma_f32_16x16x32_bf16(pf, vf1, oacc1, 0, 0, 0);
    }

    #pragma unroll
    for (int off = 1; off < 16; off <<= 1) {
        #pragma unroll
        for (int r = 0; r < 4; ++r)
            lsum[r] += __shfl_xor(lsum[r], off);
    }
    #pragma unroll
    for (int r = 0; r < 4; ++r) {
        const float inv = 1.f / lsum[r];
        ushort* op = out + ((size_t)(b * SS + q0 + g * 4 + r)) * DMODEL + h * HDIM;
        op[c]      = f2bf(oacc0[r] * inv);
        op[16 + c] = f2bf(oacc1[r] * inv);
    }
}

// ---------------------------------------------------------------------------
// x = LayerNorm(a + x) * g + beta; also writes bf16 mirror xb.
// ---------------------------------------------------------------------------
__global__ __launch_bounds__(256)
void add_ln_kernel(const float* __restrict__ a, const float* __restrict__ r,
                   const float* __restrict__ g, const float* __restrict__ beta,
                   float* __restrict__ out, ushort* __restrict__ xb)
{
    const int wave = threadIdx.x >> 6;
    const int lane = threadIdx.x & 63;
    const int row = blockIdx.x * 4 + wave;
    const size_t off = (size_t)row * DMODEL + lane * 4;

    const float4 va = *reinterpret_cast<const float4*>(a + off);
    const float4 vr = *reinterpret_cast<const float4*>(r + off);
    float v[4] = { va.x + vr.x, va.y + vr.y, va.z + vr.z, va.w + vr.w };

    float s = v[0] + v[1] + v[2] + v[3];
    #pragma unroll
    for (int o = 32; o >= 1; o >>= 1) s += __shfl_xor(s, o);
    const float mean = s * (1.f / DMODEL);

    float d0 = v[0] - mean, d1 = v[1] - mean, d2 = v[2] - mean, d3 = v[3] - mean;
    float sq = d0 * d0 + d1 * d1 + d2 * d2 + d3 * d3;
    #pragma unroll
    for (int o = 32; o >= 1; o >>= 1) sq += __shfl_xor(sq, o);
    const float inv = rsqrtf(sq * (1.f / DMODEL) + LN_EPS);

    const float4 vg = *reinterpret_cast<const float4*>(g + lane * 4);
    const float4 vb = *reinterpret_cast<const float4*>(beta + lane * 4);
    float4 o4;
    o4.x = d0 * inv * vg.x + vb.x;
    o4.y = d1 * inv * vg.y + vb.y;
    o4.z = d2 * inv * vg.z + vb.z;
    o4.w = d3 * inv * vg.w + vb.w;
    *reinterpret_cast<float4*>(out + off) = o4;
    *reinterpret_cast<uint2*>(xb + off) =
        make_uint2(pack2(o4.x, o4.y), pack2(o4.z, o4.w));
}

// ---------------------------------------------------------------------------
extern "C" void kernel_launch(void* const* d_in, const int* in_sizes, int n_in,
                              void* d_out, int out_size, void* d_ws, size_t ws_size,
                              hipStream_t stream)
{
    const float* x_in   = (const float*)d_in[0];
    const int*   maskp  = (const int*)d_in[1];
    const float* qkv_w  = (const float*)d_in[2];
    const float* qkv_b  = (const float*)d_in[3];
    const float* fc_w   = (const float*)d_in[4];
    const float* fc_b   = (const float*)d_in[5];
    const float* ln1_g  = (const float*)d_in[6];
    const float* ln1_b  = (const float*)d_in[7];
    const float* ln2_g  = (const float*)d_in[8];
    const float* ln2_b  = (const float*)d_in[9];
    const float* ff1_w  = (const float*)d_in[10];
    const float* ff1_b  = (const float*)d_in[11];
    const float* ff2_w  = (const float*)d_in[12];
    const float* ff2_b  = (const float*)d_in[13];

    float* x = (float*)d_out;                       // [4096,256] fp32 residual

    ushort* wt_qkv = (ushort*)d_ws;                 // [L][768][256]
    ushort* wt_fc  = wt_qkv + (size_t)NL * 768 * 256;
    ushort* wt_ff1 = wt_fc  + (size_t)NL * 256 * 256;
    ushort* wt_ff2 = wt_ff1 + (size_t)NL * 1024 * 256;
    ushort* big    = wt_ff2 + (size_t)NL * 256 * 1024;  // qkv_bf / h_bf (8MB)
    ushort* attn_bf= big + (size_t)MROWS * FFDIM;
    ushort* x_bf   = attn_bf + (size_t)MROWS * DMODEL;
    float*  o2     = (float*)(x_bf + (size_t)MROWS * DMODEL);

    // ---- weight prep (bf16 transposed) + input convert
    wconvT<<<dim3(24, 8, NL), 256, 0, stream>>>(qkv_w, wt_qkv, 256, 768);
    wconvT<<<dim3(8, 8, NL), 256, 0, stream>>>(fc_w, wt_fc, 256, 256);
    wconvT<<<dim3(32, 8, NL), 256, 0, stream>>>(ff1_w, wt_ff1, 256, 1024);
    wconvT<<<dim3(8, 32, NL), 256, 0, stream>>>(ff2_w, wt_ff2, 1024, 256);
    convert_x<<<dim3(MROWS * DMODEL / 1024), 256, 0, stream>>>(x_in, x, x_bf);

    for (int l = 0; l < NL; ++l) {
        // qkv (bf16 out) [4096,768]
        gemm_mfma<128, 0, 1><<<dim3(6, 32), 256, 0, stream>>>(
            x_bf, wt_qkv + (size_t)l * 768 * 256, qkv_b + l * 768,
            nullptr, big, 768, 256);
        // attention -> attn_bf [4096,256] bf16
        attn_mfma<<<dim3(32 * 64), 64, 0, stream>>>(big, maskp, attn_bf);
        // o2 = attn @ fc_w + b (fp32 out)
        gemm_mfma<64, 0, 0><<<dim3(4, 32), 256, 0, stream>>>(
            attn_bf, wt_fc + (size_t)l * 256 * 256, fc_b + l * 256,
            o2, nullptr, 256, 256);
        // x = LN1(o2 + x)
        add_ln_kernel<<<dim3(MROWS / 4), 256, 0, stream>>>(
            o2, x, ln1_g + l * DMODEL, ln1_b + l * DMODEL, x, x_bf);
        // h = relu(x @ ff1_w + b) (bf16 out) [4096,1024]
        gemm_mfma<128, 1, 1><<<dim3(8, 32), 256, 0, stream>>>(
            x_bf, wt_ff1 + (size_t)l * 1024 * 256, ff1_b + l * FFDIM,
            nullptr, big, 1024, 256);
        // o2 = h @ ff2_w + b (fp32 out)
        gemm_mfma<64, 0, 0><<<dim3(4, 32), 256, 0, stream>>>(
            big, wt_ff2 + (size_t)l * 256 * 1024, ff2_b + l * DMODEL,
            o2, nullptr, 256, 1024);
        // x = LN2(x + o2)
        add_ln_kernel<<<dim3(MROWS / 4), 256, 0, stream>>>(
            o2, x, ln2_g + l * DMODEL, ln2_b + l * DMODEL, x, x_bf);
    }
}

// Round 4
// 306.899 us; speedup vs baseline: 14.7314x; 1.4860x over previous
//
#include <hip/hip_runtime.h>
#include <hip/hip_bf16.h>
#include <math.h>

#define NL 4
#define DMODEL 256
#define NH 8
#define FFDIM 1024
#define BB 4
#define SS 1024
#define HDIM 32
#define MROWS (BB * SS)   // 4096
#define LN_EPS 1e-5f

typedef __bf16 bf16x8 __attribute__((ext_vector_type(8)));
typedef float f32x4 __attribute__((ext_vector_type(4)));
typedef unsigned int u32;

__device__ __forceinline__ ushort f2bf(float f) {
    uint u = __builtin_bit_cast(uint, f);
    u += 0x7fff + ((u >> 16) & 1);          // round-to-nearest-even
    return (ushort)(u >> 16);
}
__device__ __forceinline__ uint pack2(float a, float b) {
    return (uint)f2bf(a) | ((uint)f2bf(b) << 16);
}

// async global->LDS, 16B per lane (wave-uniform LDS base + lane*16 layout)
__device__ __forceinline__ void async_ld16(const void* g, void* l) {
    __builtin_amdgcn_global_load_lds(
        (const __attribute__((address_space(1))) u32*)g,
        (__attribute__((address_space(3))) u32*)l, 16, 0, 0);
}

// ---------------------------------------------------------------------------
// Weight convert+transpose: W[K][N] fp32 -> WT[N][K] bf16.  blockIdx.z = layer.
// ---------------------------------------------------------------------------
__global__ __launch_bounds__(256)
void wconvT(const float* __restrict__ W, ushort* __restrict__ WT, int K, int N)
{
    const int l = blockIdx.z;
    const float* src = W + (size_t)l * K * N;
    ushort* dst = WT + (size_t)l * K * N;
    __shared__ ushort t[32][33];
    const int n0 = blockIdx.x * 32, k0 = blockIdx.y * 32;
    const int tn = threadIdx.x & 31, tk8 = threadIdx.x >> 5;
    #pragma unroll
    for (int i = 0; i < 4; ++i) {
        const int k = k0 + tk8 + i * 8;
        t[tn][tk8 + i * 8] = f2bf(src[(size_t)k * N + n0 + tn]);
    }
    __syncthreads();
    #pragma unroll
    for (int i = 0; i < 4; ++i) {
        const int n = n0 + tk8 + i * 8;
        dst[(size_t)n * K + k0 + tn] = t[tk8 + i * 8][tn];
    }
}

// ---------------------------------------------------------------------------
// x_in fp32 -> x fp32 (d_out residual stream) + x_bf bf16 mirror
// ---------------------------------------------------------------------------
__global__ __launch_bounds__(256)
void convert_x(const float* __restrict__ xin, float* __restrict__ x,
               ushort* __restrict__ xb)
{
    const size_t i = ((size_t)blockIdx.x * 256 + threadIdx.x) * 4;
    const float4 v = *reinterpret_cast<const float4*>(xin + i);
    *reinterpret_cast<float4*>(x + i) = v;
    uint2 p = make_uint2(pack2(v.x, v.y), pack2(v.z, v.w));
    *reinterpret_cast<uint2*>(xb + i) = p;
}

// ---------------------------------------------------------------------------
// MFMA GEMM: C[M,N] = A[M,K](bf16) @ WT[N,K](bf16)^T + bias, opt ReLU.
// Template geometry: BM x BN tile, 4 waves arranged WM x WN.
// ---------------------------------------------------------------------------
template<int BM, int BN, int WM, int WN, int ACT, int OBF>
__global__ __launch_bounds__(256)
void gemm_mfma(const ushort* __restrict__ A, const ushort* __restrict__ WT,
               const float* __restrict__ bias, float* __restrict__ Cf,
               ushort* __restrict__ Cb, int N, int K)
{
    constexpr int BK = 64;
    constexpr int WR = BM / WM;          // rows per wave
    constexpr int WC = BN / WN;          // cols per wave
    constexpr int MR = WR / 16, NR = WC / 16;
    __shared__ __align__(16) ushort As[BM * BK];
    __shared__ __align__(16) ushort Bs[BN * BK];

    const int tid = threadIdx.x;
    const int m0 = blockIdx.y * BM, n0 = blockIdx.x * BN;
    const int wid = tid >> 6, lane = tid & 63;
    const int g = lane >> 4, c = lane & 15;
    const int wr = wid / WN, wc = wid % WN;

    f32x4 acc[MR][NR] = {};

    for (int k0 = 0; k0 < K; k0 += BK) {
        #pragma unroll
        for (int it = 0; it < (BM * BK * 2) / 4096; ++it) {
            const int o = tid * 16 + it * 4096;
            const int r = o >> 7, cb = o & 127;
            async_ld16(A + (size_t)(m0 + r) * K + k0 + (cb >> 1), (char*)As + o);
        }
        #pragma unroll
        for (int it = 0; it < (BN * BK * 2) / 4096; ++it) {
            const int o = tid * 16 + it * 4096;
            const int r = o >> 7, cb = o & 127;
            async_ld16(WT + (size_t)(n0 + r) * K + k0 + (cb >> 1), (char*)Bs + o);
        }
        __syncthreads();

        #pragma unroll
        for (int ks = 0; ks < 2; ++ks) {
            bf16x8 af[MR], bfr[NR];
            #pragma unroll
            for (int mi = 0; mi < MR; ++mi)
                af[mi] = *(const bf16x8*)&As[(wr * WR + mi * 16 + c) * BK + ks * 32 + g * 8];
            #pragma unroll
            for (int ni = 0; ni < NR; ++ni)
                bfr[ni] = *(const bf16x8*)&Bs[(wc * WC + ni * 16 + c) * BK + ks * 32 + g * 8];
            #pragma unroll
            for (int mi = 0; mi < MR; ++mi)
                #pragma unroll
                for (int ni = 0; ni < NR; ++ni)
                    acc[mi][ni] = __builtin_amdgcn_mfma_f32_16x16x32_bf16(
                        af[mi], bfr[ni], acc[mi][ni], 0, 0, 0);
        }
        __syncthreads();
    }

    float bv[NR];
    #pragma unroll
    for (int ni = 0; ni < NR; ++ni)
        bv[ni] = bias[n0 + wc * WC + ni * 16 + c];

    #pragma unroll
    for (int mi = 0; mi < MR; ++mi) {
        #pragma unroll
        for (int j = 0; j < 4; ++j) {
            const int row = m0 + wr * WR + mi * 16 + g * 4 + j;
            #pragma unroll
            for (int ni = 0; ni < NR; ++ni) {
                float v = acc[mi][ni][j] + bv[ni];
                if (ACT) v = fmaxf(v, 0.f);
                const int col = n0 + wc * WC + ni * 16 + c;
                if (OBF) Cb[(size_t)row * N + col] = f2bf(v);
                else     Cf[(size_t)row * N + col] = v;
            }
        }
    }
}

// ---------------------------------------------------------------------------
// Flash attention v2: 4 waves/block share K/V staging (QBLK=64, KVBLK=64,
// double-buffered).  Swapped QK^T: S^T = mfma(K, Q) so each lane's regs share
// one q (=lane&15) and hold 4 keys -> softmax state is a per-lane scalar;
// P stored [q][key] in per-wave LDS = directly the PV A-fragment.
// Fragment layouts (16x16x32): A row=lane&15,k=(lane>>4)*8+i; B col=lane&15,
// same k; C/D col=lane&15,row=(lane>>4)*4+reg.  [verified rounds 1-3]
// ---------------------------------------------------------------------------
__global__ __launch_bounds__(256)
void attn_mfma2(const ushort* __restrict__ qkv, const int* __restrict__ mask,
                ushort* __restrict__ out)
{
    const int tid = threadIdx.x;
    const int lane = tid & 63, wid = tid >> 6;
    const int g = lane >> 4, c = lane & 15;
    const int qblk = blockIdx.x & 15;          // 16 q-blocks of 64
    const int bh = blockIdx.x >> 4;            // 0..31
    const int h = bh & (NH - 1), b = bh >> 3;
    const int q0 = qblk * 64 + wid * 16;

    __shared__ __align__(16) ushort Kb[2][64 * 32];   // [key][d], rows 64B
    __shared__ __align__(16) ushort Vt[2][32][72];    // [d][key], stride 144B
    __shared__ __align__(16) ushort Pl[4][16][40];    // per-wave [q][key]
    __shared__ __align__(16) float  sbias[SS];        // mask -> 0 / -3.4e38

    const ushort* base = qkv + (size_t)b * SS * 768;

    {   // mask bias stage (whole S for this b)
        const int i = tid * 4;
        const int4 mv = *reinterpret_cast<const int4*>(mask + b * SS + i);
        float4 bv;
        bv.x = mv.x ? 0.f : -3.4e38f;
        bv.y = mv.y ? 0.f : -3.4e38f;
        bv.z = mv.z ? 0.f : -3.4e38f;
        bv.w = mv.w ? 0.f : -3.4e38f;
        *reinterpret_cast<float4*>(&sbias[i]) = bv;
    }

    // Q fragment (B-role): lane holds Q[q0+c][g*8 .. +8)
    const bf16x8 qfrag = *(const bf16x8*)(
        base + (size_t)(q0 + c) * 768 + h * HDIM + g * 8);

    const int kkey = tid >> 2, kdq = tid & 3;     // K staging assignment
    const int vd = tid & 31, vkg = tid >> 5;      // V staging assignment
    ushort vreg[8];

    // ---- prologue: stage chunk 0
    async_ld16(base + (size_t)kkey * 768 + DMODEL + h * HDIM + kdq * 8,
               (char*)&Kb[0][0] + tid * 16);
    {
        const ushort* vp = base + (size_t)(vkg * 8) * 768 + 2 * DMODEL + h * HDIM + vd;
        #pragma unroll
        for (int u = 0; u < 8; ++u) vreg[u] = vp[u * 768];
        uint4 pk;
        pk.x = vreg[0] | ((uint)vreg[1] << 16);
        pk.y = vreg[2] | ((uint)vreg[3] << 16);
        pk.z = vreg[4] | ((uint)vreg[5] << 16);
        pk.w = vreg[6] | ((uint)vreg[7] << 16);
        *reinterpret_cast<uint4*>(&Vt[0][vd][vkg * 8]) = pk;
    }
    __syncthreads();

    float m = -1e30f, lsum = 0.f;
    f32x4 o0 = {0.f, 0.f, 0.f, 0.f}, o1 = {0.f, 0.f, 0.f, 0.f};
    const f32x4 zf = {0.f, 0.f, 0.f, 0.f};

    for (int t = 0; t < 16; ++t) {
        const int cur = t & 1;
        if (t < 15) {   // stage t+1: K via global_load_lds, V gather to regs
            const int tn = t + 1;
            async_ld16(base + (size_t)(tn * 64 + kkey) * 768 + DMODEL + h * HDIM + kdq * 8,
                       (char*)&Kb[tn & 1][0] + tid * 16);
            const ushort* vp = base + (size_t)(tn * 64 + vkg * 8) * 768
                               + 2 * DMODEL + h * HDIM + vd;
            #pragma unroll
            for (int u = 0; u < 8; ++u) vreg[u] = vp[u * 768];
        }

        // ---- S^T tiles: rows = keys (4 per lane), cols = q (=c)
        f32x4 s[4];
        #pragma unroll
        for (int kt = 0; kt < 4; ++kt) {
            const bf16x8 kf = *(const bf16x8*)&Kb[cur][(kt * 16 + c) * 32 + g * 8];
            s[kt] = __builtin_amdgcn_mfma_f32_16x16x32_bf16(kf, qfrag, zf, 0, 0, 0);
        }
        #pragma unroll
        for (int kt = 0; kt < 4; ++kt) {
            const f32x4 bv = *reinterpret_cast<const f32x4*>(
                &sbias[t * 64 + kt * 16 + g * 4]);
            #pragma unroll
            for (int r = 0; r < 4; ++r) s[kt][r] += bv[r];
        }

        // ---- online softmax (state per lane: q = c)
        float mx = fmaxf(fmaxf(s[0][0], s[0][1]), fmaxf(s[0][2], s[0][3]));
        #pragma unroll
        for (int kt = 1; kt < 4; ++kt)
            mx = fmaxf(mx, fmaxf(fmaxf(s[kt][0], s[kt][1]),
                                 fmaxf(s[kt][2], s[kt][3])));
        mx = fmaxf(mx, __shfl_xor(mx, 16));
        mx = fmaxf(mx, __shfl_xor(mx, 32));
        const float mn = fmaxf(m, mx);
        const float sc = __expf(m - mn);
        m = mn;

        float ls = 0.f;
        #pragma unroll
        for (int kt = 0; kt < 4; ++kt) {
            const float p0 = __expf(s[kt][0] - mn);
            const float p1 = __expf(s[kt][1] - mn);
            const float p2 = __expf(s[kt][2] - mn);
            const float p3 = __expf(s[kt][3] - mn);
            ls += (p0 + p1) + (p2 + p3);
            uint2 pk2 = make_uint2(pack2(p0, p1), pack2(p2, p3));
            *reinterpret_cast<uint2*>(&Pl[wid][c][kt * 16 + g * 4]) = pk2;
        }
        ls += __shfl_xor(ls, 16);
        ls += __shfl_xor(ls, 32);
        lsum = lsum * sc + ls;

        // ---- rescale O (O rows are q = g*4+r; scale lives at lane q=c)
        float scr[4];
        #pragma unroll
        for (int r = 0; r < 4; ++r) scr[r] = __shfl(sc, g * 4 + r);
        #pragma unroll
        for (int r = 0; r < 4; ++r) { o0[r] *= scr[r]; o1[r] *= scr[r]; }

        // ---- PV: O[16q][32d] += P[16q][64k] @ V[64k][32d]
        #pragma unroll
        for (int ks = 0; ks < 2; ++ks) {
            const bf16x8 pa = *(const bf16x8*)&Pl[wid][c][ks * 32 + g * 8];
            const bf16x8 v0 = *(const bf16x8*)&Vt[cur][c][ks * 32 + g * 8];
            const bf16x8 v1 = *(const bf16x8*)&Vt[cur][16 + c][ks * 32 + g * 8];
            o0 = __builtin_amdgcn_mfma_f32_16x16x32_bf16(pa, v0, o0, 0, 0, 0);
            o1 = __builtin_amdgcn_mfma_f32_16x16x32_bf16(pa, v1, o1, 0, 0, 0);
        }

        if (t < 15) {   // commit V(t+1) to the other buffer
            uint4 pk;
            pk.x = vreg[0] | ((uint)vreg[1] << 16);
            pk.y = vreg[2] | ((uint)vreg[3] << 16);
            pk.z = vreg[4] | ((uint)vreg[5] << 16);
            pk.w = vreg[6] | ((uint)vreg[7] << 16);
            *reinterpret_cast<uint4*>(&Vt[(t + 1) & 1][vd][vkg * 8]) = pk;
        }
        __syncthreads();
    }

    // ---- finalize
    const float rs = 1.f / lsum;
    float inv[4];
    #pragma unroll
    for (int r = 0; r < 4; ++r) inv[r] = __shfl(rs, g * 4 + r);
    #pragma unroll
    for (int r = 0; r < 4; ++r) {
        ushort* op = out + (size_t)(b * SS + q0 + g * 4 + r) * DMODEL + h * HDIM;
        op[c]      = f2bf(o0[r] * inv[r]);
        op[16 + c] = f2bf(o1[r] * inv[r]);
    }
}

// ---------------------------------------------------------------------------
// x = LayerNorm(a + x) * g + beta; also writes bf16 mirror xb.
// ---------------------------------------------------------------------------
__global__ __launch_bounds__(256)
void add_ln_kernel(const float* __restrict__ a, const float* __restrict__ r,
                   const float* __restrict__ g, const float* __restrict__ beta,
                   float* __restrict__ out, ushort* __restrict__ xb)
{
    const int wave = threadIdx.x >> 6;
    const int lane = threadIdx.x & 63;
    const int row = blockIdx.x * 4 + wave;
    const size_t off = (size_t)row * DMODEL + lane * 4;

    const float4 va = *reinterpret_cast<const float4*>(a + off);
    const float4 vr = *reinterpret_cast<const float4*>(r + off);
    float v[4] = { va.x + vr.x, va.y + vr.y, va.z + vr.z, va.w + vr.w };

    float s = v[0] + v[1] + v[2] + v[3];
    #pragma unroll
    for (int o = 32; o >= 1; o >>= 1) s += __shfl_xor(s, o);
    const float mean = s * (1.f / DMODEL);

    float d0 = v[0] - mean, d1 = v[1] - mean, d2 = v[2] - mean, d3 = v[3] - mean;
    float sq = d0 * d0 + d1 * d1 + d2 * d2 + d3 * d3;
    #pragma unroll
    for (int o = 32; o >= 1; o >>= 1) sq += __shfl_xor(sq, o);
    const float inv = rsqrtf(sq * (1.f / DMODEL) + LN_EPS);

    const float4 vg = *reinterpret_cast<const float4*>(g + lane * 4);
    const float4 vb = *reinterpret_cast<const float4*>(beta + lane * 4);
    float4 o4;
    o4.x = d0 * inv * vg.x + vb.x;
    o4.y = d1 * inv * vg.y + vb.y;
    o4.z = d2 * inv * vg.z + vb.z;
    o4.w = d3 * inv * vg.w + vb.w;
    *reinterpret_cast<float4*>(out + off) = o4;
    *reinterpret_cast<uint2*>(xb + off) =
        make_uint2(pack2(o4.x, o4.y), pack2(o4.z, o4.w));
}

// ---------------------------------------------------------------------------
extern "C" void kernel_launch(void* const* d_in, const int* in_sizes, int n_in,
                              void* d_out, int out_size, void* d_ws, size_t ws_size,
                              hipStream_t stream)
{
    const float* x_in   = (const float*)d_in[0];
    const int*   maskp  = (const int*)d_in[1];
    const float* qkv_w  = (const float*)d_in[2];
    const float* qkv_b  = (const float*)d_in[3];
    const float* fc_w   = (const float*)d_in[4];
    const float* fc_b   = (const float*)d_in[5];
    const float* ln1_g  = (const float*)d_in[6];
    const float* ln1_b  = (const float*)d_in[7];
    const float* ln2_g  = (const float*)d_in[8];
    const float* ln2_b  = (const float*)d_in[9];
    const float* ff1_w  = (const float*)d_in[10];
    const float* ff1_b  = (const float*)d_in[11];
    const float* ff2_w  = (const float*)d_in[12];
    const float* ff2_b  = (const float*)d_in[13];

    float* x = (float*)d_out;                       // [4096,256] fp32 residual

    ushort* wt_qkv = (ushort*)d_ws;                 // [L][768][256]
    ushort* wt_fc  = wt_qkv + (size_t)NL * 768 * 256;
    ushort* wt_ff1 = wt_fc  + (size_t)NL * 256 * 256;
    ushort* wt_ff2 = wt_ff1 + (size_t)NL * 1024 * 256;
    ushort* big    = wt_ff2 + (size_t)NL * 256 * 1024;  // qkv_bf / h_bf (8MB)
    ushort* attn_bf= big + (size_t)MROWS * FFDIM;
    ushort* x_bf   = attn_bf + (size_t)MROWS * DMODEL;
    float*  o2     = (float*)(x_bf + (size_t)MROWS * DMODEL);

    wconvT<<<dim3(24, 8, NL), 256, 0, stream>>>(qkv_w, wt_qkv, 256, 768);
    wconvT<<<dim3(8, 8, NL), 256, 0, stream>>>(fc_w, wt_fc, 256, 256);
    wconvT<<<dim3(32, 8, NL), 256, 0, stream>>>(ff1_w, wt_ff1, 256, 1024);
    wconvT<<<dim3(8, 32, NL), 256, 0, stream>>>(ff2_w, wt_ff2, 1024, 256);
    convert_x<<<dim3(MROWS * DMODEL / 1024), 256, 0, stream>>>(x_in, x, x_bf);

    for (int l = 0; l < NL; ++l) {
        // qkv (bf16 out) [4096,768]
        gemm_mfma<64, 128, 2, 2, 0, 1><<<dim3(6, 64), 256, 0, stream>>>(
            x_bf, wt_qkv + (size_t)l * 768 * 256, qkv_b + l * 768,
            nullptr, big, 768, 256);
        // attention -> attn_bf [4096,256] bf16
        attn_mfma2<<<dim3(512), 256, 0, stream>>>(big, maskp, attn_bf);
        // o2 = attn @ fc_w + b (fp32 out)
        gemm_mfma<64, 64, 2, 2, 0, 0><<<dim3(4, 64), 256, 0, stream>>>(
            attn_bf, wt_fc + (size_t)l * 256 * 256, fc_b + l * 256,
            o2, nullptr, 256, 256);
        // x = LN1(o2 + x)
        add_ln_kernel<<<dim3(MROWS / 4), 256, 0, stream>>>(
            o2, x, ln1_g + l * DMODEL, ln1_b + l * DMODEL, x, x_bf);
        // h = relu(x @ ff1_w + b) (bf16 out) [4096,1024]
        gemm_mfma<128, 128, 2, 2, 1, 1><<<dim3(8, 32), 256, 0, stream>>>(
            x_bf, wt_ff1 + (size_t)l * 1024 * 256, ff1_b + l * FFDIM,
            nullptr, big, 1024, 256);
        // o2 = h @ ff2_w + b (fp32 out)
        gemm_mfma<64, 64, 2, 2, 0, 0><<<dim3(4, 64), 256, 0, stream>>>(
            big, wt_ff2 + (size_t)l * 256 * 1024, ff2_b + l * DMODEL,
            o2, nullptr, 256, 1024);
        // x = LN2(x + o2)
        add_ln_kernel<<<dim3(MROWS / 4), 256, 0, stream>>>(
            o2, x, ln2_g + l * DMODEL, ln2_b + l * DMODEL, x, x_bf);
    }
}